// Round 6
// baseline (395.852 us; speedup 1.0000x reference)
//
#include <hip/hip_runtime.h>
#include <hip/hip_bf16.h>
#include <stdint.h>

#define T_SEQ   2048
#define NHEAD   16
#define NPAD1   3712   // 3072 (q) + 512 (latent) + 64 (k_pe) + 64 pad -> 29*128
#define QSCALE  0.07216878364870323f   // 192^-0.5

typedef short bf16x8  __attribute__((ext_vector_type(8)));
typedef float f32x4   __attribute__((ext_vector_type(4)));
typedef float f32x16  __attribute__((ext_vector_type(16)));

__device__ __forceinline__ unsigned short f2bf(float f) {
  union { float f; uint32_t u; } v; v.f = f;
  uint32_t u = v.u;
  uint32_t r = u + 0x7FFF + ((u >> 16) & 1);   // RNE
  return (unsigned short)(r >> 16);
}

__device__ __forceinline__ void async16(const void* g, void* l) {
  __builtin_amdgcn_global_load_lds(
      (const __attribute__((address_space(1))) void*)g,
      (__attribute__((address_space(3))) void*)l, 16, 0, 0);
}

// ---------------- fused prep: convert hs + 4 weight transposes (64x64) + pad ------
__device__ __forceinline__ void tr64(const float* __restrict__ in,
    unsigned short* __restrict__ out, int R, int C, int bx, int by,
    float (*tile)[65], int tid) {
  int r0 = bx * 64, c0 = by * 64;
  int tx = tid & 63, ty = tid >> 6;            // 64 x 4
  for (int i = 0; i < 16; i++)
    tile[ty + i * 4][tx] = in[(size_t)(r0 + ty + i * 4) * C + c0 + tx];
  __syncthreads();
  for (int i = 0; i < 16; i++) {
    int c = ty + i * 4;
    out[(size_t)(c0 + c) * R + r0 + tx] = f2bf(tile[tx][c]);   // 128B runs
  }
}

__global__ __launch_bounds__(256) void prep_kernel(
    const float* __restrict__ hs, const float* __restrict__ w_q,
    const float* __restrict__ w_kv_a, const float* __restrict__ w_kv_b,
    const float* __restrict__ w_o,
    unsigned short* __restrict__ hs_bf, unsigned short* __restrict__ wcat_t,
    unsigned short* __restrict__ wkvb_t, unsigned short* __restrict__ wo_t) {
  __shared__ float tile[64][65];
  int bid = blockIdx.x, tid = threadIdx.x;
  if (bid < 4096) {                              // convert hs -> bf16
    int i = (bid * 256 + tid) * 4;
    float4 v = *(const float4*)(hs + i);
    ushort4 o; o.x = f2bf(v.x); o.y = f2bf(v.y); o.z = f2bf(v.z); o.w = f2bf(v.w);
    *(ushort4*)(hs_bf + i) = o;
  } else if (bid < 4096 + 1536) {                // w_q^T (2048x3072): 32x48
    int l = bid - 4096;
    tr64(w_q, wcat_t, 2048, 3072, l & 31, l >> 5, tile, tid);
  } else if (bid < 4096 + 1536 + 288) {          // w_kv_a^T (2048x576): 32x9
    int l = bid - (4096 + 1536);
    tr64(w_kv_a, wcat_t + (size_t)3072 * 2048, 2048, 576, l % 32, l / 32, tile, tid);
  } else if (bid < 4096 + 1536 + 288 + 512) {    // w_kv_b^T (512x4096): 8x64
    int l = bid - (4096 + 1536 + 288);
    tr64(w_kv_b, wkvb_t, 512, 4096, l & 7, l >> 3, tile, tid);
  } else if (bid < 4096 + 1536 + 288 + 512 + 1024) {   // w_o^T (2048x2048): 32x32
    int l = bid - (4096 + 1536 + 288 + 512);
    tr64(w_o, wo_t, 2048, 2048, l & 31, l >> 5, tile, tid);
  } else {                                       // zero pad rows 3648..3711 of wcat_t
    int l = bid - (4096 + 1536 + 288 + 512 + 1024);
    uint4 z = (uint4){0, 0, 0, 0};
    *(uint4*)(wcat_t + (size_t)3648 * 2048 + (size_t)(l * 256 + tid) * 8) = z;
  }
}

// ---------------- GEMM: C(MxN) = A(MxK) bf16 @ B^T(NxK) bf16, BK=64 --------------
// TM x 128 tile, 4 waves of (TM/2)x64, double-buffered global_load_lds staging,
// 1 barrier per 64-k step (2 MFMA k-substeps per buffer).
// MODE 0: f32 C.  MODE 1: bf16 C.
// MODE 2 (gemm1/MLA-Q): n0<3072 -> q region: d<128 -> q_full bf16 (scaled);
//         d>=128 -> qpe f32 (scaled). n0>=3072 -> lat f32 [row][col-3072].
// MODE 3 (gemm2/KV): c=col&255: c<128 -> k_full[h][row][c] bf16; else v_n bf16.
template<int TM, int MODE>
__global__ __launch_bounds__(256) void gemm_bt_kernel(
    const unsigned short* __restrict__ A, const unsigned short* __restrict__ B,
    void* __restrict__ Cv, void* __restrict__ aux0, void* __restrict__ aux1,
    int M, int N, int K) {
  constexpr int MT = TM / 32;
  __shared__ __align__(16) unsigned short Asm[2][TM * 64];
  __shared__ __align__(16) unsigned short Bsm[2][128 * 64];
  int tid = threadIdx.x, wid = tid >> 6, lane = tid & 63;
  int lrow = lane & 15, lquad = lane >> 4;
  int m0 = blockIdx.x * TM, n0 = blockIdx.y * 128;
  int wm = (wid & 1) * (TM / 2), wn = (wid >> 1) * 64;

  int row_s = tid >> 2, cc_s = tid & 3;
  const unsigned short* Ag = A + (size_t)(m0 + row_s) * K + cc_s * 8;
  const unsigned short* Bg = B + (size_t)(n0 + row_s) * K + cc_s * 8;
  const size_t rowK64 = (size_t)64 * K;

  f32x4 acc[MT][4];
  for (int i = 0; i < MT; i++) for (int j = 0; j < 4; j++) acc[i][j] = (f32x4){0.f,0.f,0.f,0.f};

  // stage buffer `buf` with k-offset kk
  auto stage = [&](int kk, int buf) {
    async16(Ag + kk,      &Asm[buf][tid * 8]);
    async16(Ag + kk + 32, &Asm[buf][(256 + tid) * 8]);
    if (TM == 128) {
      async16(Ag + kk + rowK64,      &Asm[buf][(512 + tid) * 8]);
      async16(Ag + kk + rowK64 + 32, &Asm[buf][(768 + tid) * 8]);
    }
    async16(Bg + kk,      &Bsm[buf][tid * 8]);
    async16(Bg + kk + 32, &Bsm[buf][(256 + tid) * 8]);
    async16(Bg + kk + rowK64,      &Bsm[buf][(512 + tid) * 8]);
    async16(Bg + kk + rowK64 + 32, &Bsm[buf][(768 + tid) * 8]);
  };

  stage(0, 0);
  // frag base offsets (shorts): slot(m,kc8) = (m>>6)*512 + (kc8>>2)*256 + (m&63)*4 + (kc8&3)
  int abase = (wm >> 6) * 4096 + ((wm & 63) + lrow) * 32 + lquad * 8;
  int bbase = (wn >> 6) * 4096 + lrow * 32 + lquad * 8;   // wn&63 == 0 always

  int cur = 0;
  for (int k0 = 0; k0 < K; k0 += 64) {
    __syncthreads();                      // drains DMA for buf[cur]; prev readers done
    if (k0 + 64 < K) stage(k0 + 64, cur ^ 1);
    const unsigned short* As = Asm[cur];
    const unsigned short* Bs = Bsm[cur];
    #pragma unroll
    for (int step = 0; step < 2; step++) {
      bf16x8 af[MT], bfr[4];
      #pragma unroll
      for (int mt = 0; mt < MT; mt++)
        af[mt] = *(const bf16x8*)(As + abase + step * 2048 + mt * 512);
      #pragma unroll
      for (int nt = 0; nt < 4; nt++)
        bfr[nt] = *(const bf16x8*)(Bs + bbase + step * 2048 + nt * 512);
      #pragma unroll
      for (int mt = 0; mt < MT; mt++)
        #pragma unroll
        for (int nt = 0; nt < 4; nt++)
          acc[mt][nt] = __builtin_amdgcn_mfma_f32_16x16x32_bf16(af[mt], bfr[nt], acc[mt][nt], 0, 0, 0);
    }
    cur ^= 1;
  }

  for (int mt = 0; mt < MT; mt++)
    for (int nt = 0; nt < 4; nt++) {
      int row = m0 + wm + mt * 16 + lquad * 4;
      int col = n0 + wn + nt * 16 + lrow;
      for (int r = 0; r < 4; r++) {
        float v = acc[mt][nt][r];
        if (MODE == 0) {
          ((float*)Cv)[(size_t)(row + r) * N + col] = v;
        } else if (MODE == 1) {
          ((unsigned short*)Cv)[(size_t)(row + r) * N + col] = f2bf(v);
        } else if (MODE == 2) {
          if (n0 < 3072) {
            int h = (unsigned)col / 192u, d = col - h * 192;
            if (d < 128)
              ((unsigned short*)Cv)[((size_t)h * T_SEQ + row + r) * 192 + d] = f2bf(v * QSCALE);
            else
              ((float*)aux0)[(size_t)(row + r) * 1024 + h * 64 + (d - 128)] = v * QSCALE;
          } else {
            ((float*)aux1)[(size_t)(row + r) * 640 + (col - 3072)] = v;
          }
        } else {  // MODE 3
          int h = col >> 8, c = col & 255;
          if (c < 128)
            ((unsigned short*)Cv)[((size_t)h * T_SEQ + row + r) * 192 + c] = f2bf(v);
          else
            ((unsigned short*)aux0)[(size_t)(row + r) * 2048 + h * 128 + (c - 128)] = f2bf(v);
        }
      }
    }
}

// ---------------- postproc1: rmsnorm(latent) + rope(k_pe, q_pe) ----------------
__global__ __launch_bounds__(256) void postproc1_kernel(
    const float* __restrict__ lat,        // T x 640 f32 (latent 512 | k_pe 64 | pad)
    const float* __restrict__ qpe,        // T x 1024 f32 (pre-scaled)
    const float* __restrict__ ln_w,       // 512
    const int* __restrict__ positions,    // T (int32)
    unsigned short* __restrict__ kv_a,    // T x 512 bf16
    unsigned short* __restrict__ q_full,  // NH x T x 192 bf16 (writes d=128..191)
    unsigned short* __restrict__ k_pe)    // T x 64 bf16 (roped)
{
  int t = blockIdx.x, tid = threadIdx.x;
  const float* row = lat + (size_t)t * 640;

  float v0 = row[tid], v1 = row[256 + tid];
  float ss = v0 * v0 + v1 * v1;
  for (int m = 1; m < 64; m <<= 1) ss += __shfl_xor(ss, m, 64);
  __shared__ float red[4];
  if ((tid & 63) == 0) red[tid >> 6] = ss;
  __shared__ float kro[64], cf[32], sf[32];
  float pos = (float)positions[t];
  if (tid < 32) {
    float inv_freq = powf(10000.f, -(float)(2 * tid) / 64.f);
    float c, s; sincosf(pos * inv_freq, &s, &c);
    cf[tid] = c; sf[tid] = s;
    float x1 = row[512 + 2 * tid], x2 = row[512 + 2 * tid + 1];
    kro[2 * tid]     = x1 * c - x2 * s;
    kro[2 * tid + 1] = x2 * c + x1 * s;
  }
  __syncthreads();
  float rstd = rsqrtf((red[0] + red[1] + red[2] + red[3]) * (1.f / 512.f) + 1e-6f);
  kv_a[(size_t)t * 512 + tid]       = f2bf(v0 * rstd * ln_w[tid]);
  kv_a[(size_t)t * 512 + 256 + tid] = f2bf(v1 * rstd * ln_w[256 + tid]);
  if (tid < 64) k_pe[(size_t)t * 64 + tid] = f2bf(kro[tid]);

  #pragma unroll
  for (int ii = 0; ii < 2; ii++) {              // q_pe rope (already scaled)
    int i = tid + ii * 256;                     // over NH*32
    int h = i >> 5, p = i & 31;
    float c = cf[p], s = sf[p];
    float x1 = qpe[(size_t)t * 1024 + h * 64 + 2 * p];
    float x2 = qpe[(size_t)t * 1024 + h * 64 + 2 * p + 1];
    q_full[((size_t)h * T_SEQ + t) * 192 + 128 + 2 * p]     = f2bf(x1 * c - x2 * s);
    q_full[((size_t)h * T_SEQ + t) * 192 + 128 + 2 * p + 1] = f2bf(x2 * c + x1 * s);
  }
}

// ---------------- kvpost: k_pe merge into k_full + v transpose ----------------
__global__ __launch_bounds__(256) void kvpost_kernel(
    const unsigned short* __restrict__ k_pe,   // T x 64 bf16
    const unsigned short* __restrict__ v_n,    // T x 2048 bf16 ([t][h*128+d])
    unsigned short* __restrict__ k_full,       // NH x T x 192 bf16 (writes 128..191)
    unsigned short* __restrict__ v_t) {        // NH x 128 x T bf16
  __shared__ unsigned short tile[32][41];
  int bid = blockIdx.x, tid = threadIdx.x;
  if (bid < 1024) {                            // k_pe broadcast: NH*T*8 chunks
    int idx = bid * 256 + tid;
    int cc = idx & 7, t = (idx >> 3) & (T_SEQ - 1), h = idx >> 14;
    uint4 v = *(const uint4*)(k_pe + (size_t)t * 64 + cc * 8);
    *(uint4*)(k_full + ((size_t)h * T_SEQ + t) * 192 + 128 + cc * 8) = v;
  } else {                                     // vtrans: 64 x 4 x 16
    int l = bid - 1024;
    int h = l >> 8, t0 = (l & 63) * 32, d0 = ((l >> 6) & 3) * 32;
    int tx = tid & 31, ty = tid >> 5;
    for (int i = 0; i < 4; i++)
      tile[ty + i * 8][tx] = v_n[(size_t)(t0 + ty + i * 8) * 2048 + h * 128 + d0 + tx];
    __syncthreads();
    for (int i = 0; i < 4; i++)
      v_t[((size_t)h * 128 + d0 + ty + i * 8) * T_SEQ + t0 + tx] = tile[tx][ty + i * 8];
  }
}

// ---------------- flash attention: BM=64, BN=64, 32x32x16 MFMA (r5 structure) ----
#define PP 76
__global__ __launch_bounds__(256, 2) void flash_kernel(
    const unsigned short* __restrict__ q_full,  // NH x T x 192 (pre-scaled)
    const unsigned short* __restrict__ k_full,  // NH x T x 192
    const unsigned short* __restrict__ v_t,     // NH x 128 x T
    unsigned short* __restrict__ attn_out)      // T x 2048
{
  __shared__ __align__(16) unsigned short Ksm[2][1536 * 8];  // 49152 B
  __shared__ __align__(16) unsigned short Vsm[1024 * 8];     // 16384 B
  __shared__ __align__(16) unsigned short Psm[64 * PP];      //  9728 B
  __shared__ float Lred[2][64];
  int h = blockIdx.x;
  int y = blockIdx.y;
  int qb = (y < 16) ? (31 - y) : (y - 16);     // balanced pairing (sum 31)
  int tid = threadIdx.x, wid = tid >> 6, lane = tid & 63;
  int l31 = lane & 31, l5 = lane >> 5, x7 = l31 & 7;
  int rq = wid & 1, kq = wid >> 1;

  const unsigned short* kh = k_full + (size_t)h * T_SEQ * 192;
  const unsigned short* vh = v_t    + (size_t)h * 128 * T_SEQ;

  int gK[6], gV[4];
  #pragma unroll
  for (int j = 0; j < 6; j++) {
    int s = tid + j * 256, row = s / 24, cm = s - row * 24;
    gK[j] = row * 192 + (cm ^ (row & 7)) * 8;
  }
  #pragma unroll
  for (int j = 0; j < 4; j++) {
    int s = tid + j * 256, d = s >> 3;
    gV[j] = d * T_SEQ + ((s & 7) ^ (d & 7)) * 8;
  }
  int kxo[12];
  #pragma unroll
  for (int kc = 0; kc < 12; kc++)
    kxo[kc] = (kq * 32 + l31) * 192 + ((kc * 2 + l5) ^ x7) * 8;
  int vxb[2];
  #pragma unroll
  for (int ntv = 0; ntv < 2; ntv++) vxb[ntv] = (kq * 64 + ntv * 32 + l31) * 64;

  bf16x8 qf[12];
  {
    const unsigned short* qrow =
        q_full + ((size_t)h * T_SEQ + qb * 64 + rq * 32 + l31) * 192 + l5 * 8;
    #pragma unroll
    for (int kc = 0; kc < 12; kc++) qf[kc] = *(const bf16x8*)(qrow + kc * 16);
  }
  f32x16 oacc[2];
  for (int i = 0; i < 2; i++) oacc[i] = (f32x16)(0.f);
  float lsum[16];
  #pragma unroll
  for (int r = 0; r < 16; r++) lsum[r] = 0.f;
  int rl[16];
  #pragma unroll
  for (int r = 0; r < 16; r++) rl[r] = (r & 3) + 8 * (r >> 2) + 4 * l5;

  #pragma unroll
  for (int j = 0; j < 6; j++) async16(kh + gK[j], &Ksm[0][(tid + j * 256) * 8]);

  int cur = 0;
  for (int kb = 0; kb <= qb; kb++) {
    __syncthreads();                            // K[cur] ready; prev PV readers done
    {
      const unsigned short* vb = vh + kb * 64;
      #pragma unroll
      for (int j = 0; j < 4; j++) async16(vb + gV[j], &Vsm[(tid + j * 256) * 8]);
    }
    const unsigned short* Ks = Ksm[cur];
    f32x16 sacc = (f32x16)(0.f);
    #pragma unroll
    for (int kc = 0; kc < 12; kc++) {
      bf16x8 kf = *(const bf16x8*)(Ks + kxo[kc]);
      sacc = __builtin_amdgcn_mfma_f32_32x32x16_bf16(qf[kc], kf, sacc, 0, 0, 0);
    }
    if (kb == qb) {
      int col_g = kb * 64 + kq * 32 + l31;
      int row_b = qb * 64 + rq * 32;
      #pragma unroll
      for (int r = 0; r < 16; r++)
        if (col_g > row_b + rl[r]) sacc[r] = -1e30f;
    }
    #pragma unroll
    for (int r = 0; r < 16; r++) {
      float p = __expf(sacc[r]);
      sacc[r] = p;
      lsum[r] += p;
    }
    #pragma unroll
    for (int r = 0; r < 16; r++)
      Psm[(rq * 32 + rl[r]) * PP + kq * 32 + l31] = f2bf(sacc[r]);
    __syncthreads();                            // V ready, P visible, K[cur] reads done
    if (kb < qb) {
      const unsigned short* kb1 = kh + (size_t)(kb + 1) * 64 * 192;
      #pragma unroll
      for (int j = 0; j < 6; j++) async16(kb1 + gK[j], &Ksm[cur ^ 1][(tid + j * 256) * 8]);
    }
    #pragma unroll
    for (int kc = 0; kc < 4; kc++) {
      bf16x8 pf = *(const bf16x8*)(Psm + (rq * 32 + l31) * PP + kc * 16 + l5 * 8);
      #pragma unroll
      for (int ntv = 0; ntv < 2; ntv++) {
        bf16x8 vf = *(const bf16x8*)(Vsm + vxb[ntv] + ((kc * 2 + l5) ^ x7) * 8);
        oacc[ntv] = __builtin_amdgcn_mfma_f32_32x32x16_bf16(pf, vf, oacc[ntv], 0, 0, 0);
      }
    }
    cur ^= 1;
  }

  #pragma unroll
  for (int r = 0; r < 16; r++) {
    float s = lsum[r];
    s += __shfl_xor(s, 1, 64);
    s += __shfl_xor(s, 2, 64);
    s += __shfl_xor(s, 4, 64);
    s += __shfl_xor(s, 8, 64);
    s += __shfl_xor(s, 16, 64);
    lsum[r] = s;
  }
  if (l31 == 0)
    #pragma unroll
    for (int r = 0; r < 16; r++) Lred[kq][rq * 32 + rl[r]] = lsum[r];
  __syncthreads();
  #pragma unroll
  for (int r = 0; r < 16; r++) {
    int row_l = rq * 32 + rl[r];
    float inv = 1.f / (Lred[0][row_l] + Lred[1][row_l]);
    int row_g = qb * 64 + row_l;
    #pragma unroll
    for (int ntv = 0; ntv < 2; ntv++)
      attn_out[(size_t)row_g * 2048 + h * 128 + kq * 64 + ntv * 32 + l31] =
          f2bf(oacc[ntv][r] * inv);
  }
}

// ---------------- launch ----------------
extern "C" void kernel_launch(void* const* d_in, const int* in_sizes, int n_in,
                              void* d_out, int out_size, void* d_ws, size_t ws_size,
                              hipStream_t stream) {
  const int*   positions = (const int*)d_in[0];
  const float* hs     = (const float*)d_in[1];
  const float* w_q    = (const float*)d_in[2];
  const float* w_kv_a = (const float*)d_in[3];
  const float* ln_w   = (const float*)d_in[4];
  const float* w_kv_b = (const float*)d_in[5];
  const float* w_o    = (const float*)d_in[6];
  float* out = (float*)d_out;

  char* ws = (char*)d_ws;
  size_t off = 0;
  auto alloc = [&](size_t bytes) { void* p = ws + off; off += (bytes + 255) & ~(size_t)255; return p; };
  unsigned short* hs_bf   = (unsigned short*)alloc((size_t)2048 * 2048 * 2);
  unsigned short* wcat_t  = (unsigned short*)alloc((size_t)NPAD1 * 2048 * 2);
  float*          lat     = (float*)alloc((size_t)2048 * 640 * 4);
  float*          qpe     = (float*)alloc((size_t)2048 * 1024 * 4);
  unsigned short* kv_a_bf = (unsigned short*)alloc((size_t)2048 * 512 * 2);
  unsigned short* wkvb_t  = (unsigned short*)alloc((size_t)4096 * 512 * 2);
  unsigned short* q_full  = (unsigned short*)alloc((size_t)NHEAD * 2048 * 192 * 2);
  unsigned short* k_pe    = (unsigned short*)alloc((size_t)2048 * 64 * 2);
  unsigned short* k_full  = (unsigned short*)alloc((size_t)NHEAD * 2048 * 192 * 2);
  unsigned short* v_n     = (unsigned short*)alloc((size_t)2048 * 2048 * 2);
  unsigned short* v_t     = (unsigned short*)alloc((size_t)NHEAD * 128 * 2048 * 2);
  unsigned short* attn_o  = (unsigned short*)alloc((size_t)2048 * 2048 * 2);
  unsigned short* wo_t    = (unsigned short*)alloc((size_t)2048 * 2048 * 2);

  prep_kernel<<<7520, 256, 0, stream>>>(hs, w_q, w_kv_a, w_kv_b, w_o,
                                        hs_bf, wcat_t, wkvb_t, wo_t);
  gemm_bt_kernel<128, 2><<<dim3(16, 29), 256, 0, stream>>>(
      hs_bf, wcat_t, q_full, qpe, lat, 2048, NPAD1, 2048);
  postproc1_kernel<<<2048, 256, 0, stream>>>(lat, qpe, ln_w, positions, kv_a_bf, q_full, k_pe);
  gemm_bt_kernel<128, 3><<<dim3(16, 32), 256, 0, stream>>>(
      kv_a_bf, wkvb_t, k_full, v_n, nullptr, 2048, 4096, 512);
  kvpost_kernel<<<5120, 256, 0, stream>>>(k_pe, v_n, k_full, v_t);
  flash_kernel<<<dim3(16, 32), 256, 0, stream>>>(q_full, k_full, v_t, attn_o);
  gemm_bt_kernel<64, 0><<<dim3(32, 16), 256, 0, stream>>>(
      attn_o, wo_t, out, nullptr, nullptr, 2048, 2048, 2048);
}

// Round 7
// 392.166 us; speedup vs baseline: 1.0094x; 1.0094x over previous
//
#include <hip/hip_runtime.h>
#include <hip/hip_bf16.h>
#include <stdint.h>

#define T_SEQ   2048
#define NHEAD   16
#define NPAD1   3712   // 3072 (q) + 512 (latent) + 64 (k_pe) + 64 pad -> 29*128
#define QSCALE  0.07216878364870323f   // 192^-0.5

typedef short bf16x8  __attribute__((ext_vector_type(8)));
typedef float f32x4   __attribute__((ext_vector_type(4)));
typedef float f32x16  __attribute__((ext_vector_type(16)));

__device__ __forceinline__ unsigned short f2bf(float f) {
  union { float f; uint32_t u; } v; v.f = f;
  uint32_t u = v.u;
  uint32_t r = u + 0x7FFF + ((u >> 16) & 1);   // RNE
  return (unsigned short)(r >> 16);
}
__device__ __forceinline__ float bf2f(unsigned short b) {
  union { uint32_t u; float f; } v; v.u = ((uint32_t)b) << 16; return v.f;
}

__device__ __forceinline__ void async16(const void* g, void* l) {
  __builtin_amdgcn_global_load_lds(
      (const __attribute__((address_space(1))) void*)g,
      (__attribute__((address_space(3))) void*)l, 16, 0, 0);
}

// ---------------- fused prep: convert hs + 4 weight transposes (64x64) + pad ------
__device__ __forceinline__ void tr64(const float* __restrict__ in,
    unsigned short* __restrict__ out, int R, int C, int bx, int by,
    float (*tile)[65], int tid) {
  int r0 = bx * 64, c0 = by * 64;
  int tx = tid & 63, ty = tid >> 6;            // 64 x 4
  for (int i = 0; i < 16; i++)
    tile[ty + i * 4][tx] = in[(size_t)(r0 + ty + i * 4) * C + c0 + tx];
  __syncthreads();
  for (int i = 0; i < 16; i++) {
    int c = ty + i * 4;
    out[(size_t)(c0 + c) * R + r0 + tx] = f2bf(tile[tx][c]);   // 128B runs
  }
}

__global__ __launch_bounds__(256) void prep_kernel(
    const float* __restrict__ hs, const float* __restrict__ w_q,
    const float* __restrict__ w_kv_a, const float* __restrict__ w_kv_b,
    const float* __restrict__ w_o,
    unsigned short* __restrict__ hs_bf, unsigned short* __restrict__ wcat_t,
    unsigned short* __restrict__ wkvb_t, unsigned short* __restrict__ wo_t) {
  __shared__ float tile[64][65];
  int bid = blockIdx.x, tid = threadIdx.x;
  if (bid < 4096) {                              // convert hs -> bf16
    int i = (bid * 256 + tid) * 4;
    float4 v = *(const float4*)(hs + i);
    ushort4 o; o.x = f2bf(v.x); o.y = f2bf(v.y); o.z = f2bf(v.z); o.w = f2bf(v.w);
    *(ushort4*)(hs_bf + i) = o;
  } else if (bid < 4096 + 1536) {                // w_q^T (2048x3072): 32x48
    int l = bid - 4096;
    tr64(w_q, wcat_t, 2048, 3072, l & 31, l >> 5, tile, tid);
  } else if (bid < 4096 + 1536 + 288) {          // w_kv_a^T (2048x576): 32x9
    int l = bid - (4096 + 1536);
    tr64(w_kv_a, wcat_t + (size_t)3072 * 2048, 2048, 576, l % 32, l / 32, tile, tid);
  } else if (bid < 4096 + 1536 + 288 + 512) {    // w_kv_b^T (512x4096): 8x64
    int l = bid - (4096 + 1536 + 288);
    tr64(w_kv_b, wkvb_t, 512, 4096, l & 7, l >> 3, tile, tid);
  } else if (bid < 4096 + 1536 + 288 + 512 + 1024) {   // w_o^T (2048x2048): 32x32
    int l = bid - (4096 + 1536 + 288 + 512);
    tr64(w_o, wo_t, 2048, 2048, l & 31, l >> 5, tile, tid);
  } else {                                       // zero pad rows 3648..3711 of wcat_t
    int l = bid - (4096 + 1536 + 288 + 512 + 1024);
    uint4 z = (uint4){0, 0, 0, 0};
    *(uint4*)(wcat_t + (size_t)3648 * 2048 + (size_t)(l * 256 + tid) * 8) = z;
  }
}

// ---------------- GEMM: C(MxN) = A(MxK) bf16 @ B^T(NxK) bf16, BK=64 --------------
// TM x 128 tile, 4 waves of (TM/2)x64, double-buffered global_load_lds staging,
// 1 barrier per 64-k step (2 MFMA k-substeps per buffer).
// MODE 0: f32 C row-major.  MODE 1: bf16 C row-major.
// MODE 2 (gemm1): n0<3072 -> q_cat bf16 [row][col] (xQSCALE);
//                 n0>=3072 -> lat f32 [row][col-3072]. (both tile-aligned, no scatter)
template<int TM, int MODE>
__global__ __launch_bounds__(256) void gemm_bt_kernel(
    const unsigned short* __restrict__ A, const unsigned short* __restrict__ B,
    void* __restrict__ Cv, void* __restrict__ aux0,
    int M, int N, int K) {
  constexpr int MT = TM / 32;
  __shared__ __align__(16) unsigned short Asm[2][TM * 64];
  __shared__ __align__(16) unsigned short Bsm[2][128 * 64];
  int tid = threadIdx.x, wid = tid >> 6, lane = tid & 63;
  int lrow = lane & 15, lquad = lane >> 4;
  int m0 = blockIdx.x * TM, n0 = blockIdx.y * 128;
  int wm = (wid & 1) * (TM / 2), wn = (wid >> 1) * 64;

  int row_s = tid >> 2, cc_s = tid & 3;
  const unsigned short* Ag = A + (size_t)(m0 + row_s) * K + cc_s * 8;
  const unsigned short* Bg = B + (size_t)(n0 + row_s) * K + cc_s * 8;
  const size_t rowK64 = (size_t)64 * K;

  f32x4 acc[MT][4];
  for (int i = 0; i < MT; i++) for (int j = 0; j < 4; j++) acc[i][j] = (f32x4){0.f,0.f,0.f,0.f};

  auto stage = [&](int kk, int buf) {
    async16(Ag + kk,      &Asm[buf][tid * 8]);
    async16(Ag + kk + 32, &Asm[buf][(256 + tid) * 8]);
    if (TM == 128) {
      async16(Ag + kk + rowK64,      &Asm[buf][(512 + tid) * 8]);
      async16(Ag + kk + rowK64 + 32, &Asm[buf][(768 + tid) * 8]);
    }
    async16(Bg + kk,      &Bsm[buf][tid * 8]);
    async16(Bg + kk + 32, &Bsm[buf][(256 + tid) * 8]);
    async16(Bg + kk + rowK64,      &Bsm[buf][(512 + tid) * 8]);
    async16(Bg + kk + rowK64 + 32, &Bsm[buf][(768 + tid) * 8]);
  };

  stage(0, 0);
  int abase = (wm >> 6) * 4096 + ((wm & 63) + lrow) * 32 + lquad * 8;
  int bbase = (wn >> 6) * 4096 + lrow * 32 + lquad * 8;

  int cur = 0;
  for (int k0 = 0; k0 < K; k0 += 64) {
    __syncthreads();                      // drains DMA for buf[cur]; prev readers done
    if (k0 + 64 < K) stage(k0 + 64, cur ^ 1);
    const unsigned short* As = Asm[cur];
    const unsigned short* Bs = Bsm[cur];
    #pragma unroll
    for (int step = 0; step < 2; step++) {
      bf16x8 af[MT], bfr[4];
      #pragma unroll
      for (int mt = 0; mt < MT; mt++)
        af[mt] = *(const bf16x8*)(As + abase + step * 2048 + mt * 512);
      #pragma unroll
      for (int nt = 0; nt < 4; nt++)
        bfr[nt] = *(const bf16x8*)(Bs + bbase + step * 2048 + nt * 512);
      #pragma unroll
      for (int mt = 0; mt < MT; mt++)
        #pragma unroll
        for (int nt = 0; nt < 4; nt++)
          acc[mt][nt] = __builtin_amdgcn_mfma_f32_16x16x32_bf16(af[mt], bfr[nt], acc[mt][nt], 0, 0, 0);
    }
    cur ^= 1;
  }

  for (int mt = 0; mt < MT; mt++)
    for (int nt = 0; nt < 4; nt++) {
      int row = m0 + wm + mt * 16 + lquad * 4;
      int col = n0 + wn + nt * 16 + lrow;
      for (int r = 0; r < 4; r++) {
        float v = acc[mt][nt][r];
        if (MODE == 0) {
          ((float*)Cv)[(size_t)(row + r) * N + col] = v;
        } else if (MODE == 1) {
          ((unsigned short*)Cv)[(size_t)(row + r) * N + col] = f2bf(v);
        } else {  // MODE 2
          if (n0 < 3072)
            ((unsigned short*)Cv)[(size_t)(row + r) * 3072 + col] = f2bf(v * QSCALE);
          else
            ((float*)aux0)[(size_t)(row + r) * 640 + (col - 3072)] = v;
        }
      }
    }
}

// ---------------- postproc1: rmsnorm(latent) + rope(k_pe) + rope(q_pe in-place) ---
__global__ __launch_bounds__(256) void postproc1_kernel(
    const float* __restrict__ lat,        // T x 640 f32 (latent 512 | k_pe 64 | pad)
    const float* __restrict__ ln_w,       // 512
    const int* __restrict__ positions,    // T (int32)
    unsigned short* __restrict__ kv_a,    // T x 512 bf16
    unsigned short* __restrict__ q_cat,   // T x 3072 bf16 (ropes cols h*192+128..191)
    unsigned short* __restrict__ k_pe)    // T x 64 bf16 (roped)
{
  int t = blockIdx.x, tid = threadIdx.x;
  const float* row = lat + (size_t)t * 640;

  float v0 = row[tid], v1 = row[256 + tid];
  float ss = v0 * v0 + v1 * v1;
  for (int m = 1; m < 64; m <<= 1) ss += __shfl_xor(ss, m, 64);
  __shared__ float red[4];
  if ((tid & 63) == 0) red[tid >> 6] = ss;
  __shared__ float kro[64], cf[32], sf[32];
  float pos = (float)positions[t];
  if (tid < 32) {
    float inv_freq = powf(10000.f, -(float)(2 * tid) / 64.f);
    float c, s; sincosf(pos * inv_freq, &s, &c);
    cf[tid] = c; sf[tid] = s;
    float x1 = row[512 + 2 * tid], x2 = row[512 + 2 * tid + 1];
    kro[2 * tid]     = x1 * c - x2 * s;
    kro[2 * tid + 1] = x2 * c + x1 * s;
  }
  __syncthreads();
  float rstd = rsqrtf((red[0] + red[1] + red[2] + red[3]) * (1.f / 512.f) + 1e-6f);
  kv_a[(size_t)t * 512 + tid]       = f2bf(v0 * rstd * ln_w[tid]);
  kv_a[(size_t)t * 512 + 256 + tid] = f2bf(v1 * rstd * ln_w[256 + tid]);
  if (tid < 64) k_pe[(size_t)t * 64 + tid] = f2bf(kro[tid]);

  #pragma unroll
  for (int ii = 0; ii < 2; ii++) {              // q_pe rope in place (pre-scaled)
    int i = tid + ii * 256;                     // over NH*32 pairs
    int h = i >> 5, p = i & 31;
    float c = cf[p], s = sf[p];
    unsigned short* qp = q_cat + (size_t)t * 3072 + h * 192 + 128 + 2 * p;
    float x1 = bf2f(qp[0]), x2 = bf2f(qp[1]);
    qp[0] = f2bf(x1 * c - x2 * s);
    qp[1] = f2bf(x2 * c + x1 * s);
  }
}

// ---------------- kvpost: kpack (k_full) + vtrans (v_t) ----------------
__global__ __launch_bounds__(256) void kvpost_kernel(
    const unsigned short* __restrict__ kv_b,   // T x 4096 bf16
    const unsigned short* __restrict__ k_pe,   // T x 64 bf16
    unsigned short* __restrict__ k_full,       // NH x T x 192 bf16
    unsigned short* __restrict__ v_t) {        // NH x 128 x T bf16
  __shared__ unsigned short tile[32][41];
  int bid = blockIdx.x, tid = threadIdx.x;
  if (bid < 3072) {                            // kpack: NH*T*24 chunks of 8 shorts
    int idx = bid * 256 + tid;
    int cc = idx % 24, rest = idx / 24;
    int t = rest & (T_SEQ - 1), h = rest >> 11;
    uint4 v = (cc < 16)
        ? *(const uint4*)(kv_b + (size_t)t * 4096 + h * 256 + cc * 8)
        : *(const uint4*)(k_pe + (size_t)t * 64 + (cc - 16) * 8);
    *(uint4*)(k_full + (size_t)idx * 8) = v;
  } else {                                     // vtrans: 64 x 4 x 16
    int l = bid - 3072;
    int h = l >> 8, t0 = (l & 63) * 32, d0 = ((l >> 6) & 3) * 32;
    int tx = tid & 31, ty = tid >> 5;
    for (int i = 0; i < 4; i++)
      tile[ty + i * 8][tx] = kv_b[(size_t)(t0 + ty + i * 8) * 4096 + h * 256 + 128 + d0 + tx];
    __syncthreads();
    for (int i = 0; i < 4; i++)
      v_t[((size_t)h * 128 + d0 + ty + i * 8) * T_SEQ + t0 + tx] = tile[tx][ty + i * 8];
  }
}

// ---------------- flash attention: BM=64, BN=64, 32x32x16 MFMA (r5 structure) ----
#define PP 76
__global__ __launch_bounds__(256, 2) void flash_kernel(
    const unsigned short* __restrict__ q_cat,   // T x 3072 (pre-scaled, roped)
    const unsigned short* __restrict__ k_full,  // NH x T x 192
    const unsigned short* __restrict__ v_t,     // NH x 128 x T
    unsigned short* __restrict__ attn_out)      // T x 2048
{
  __shared__ __align__(16) unsigned short Ksm[2][1536 * 8];  // 49152 B
  __shared__ __align__(16) unsigned short Vsm[1024 * 8];     // 16384 B
  __shared__ __align__(16) unsigned short Psm[64 * PP];      //  9728 B
  __shared__ float Lred[2][64];
  int h = blockIdx.x;
  int y = blockIdx.y;
  int qb = (y < 16) ? (31 - y) : (y - 16);     // balanced pairing (sum 31)
  int tid = threadIdx.x, wid = tid >> 6, lane = tid & 63;
  int l31 = lane & 31, l5 = lane >> 5, x7 = l31 & 7;
  int rq = wid & 1, kq = wid >> 1;

  const unsigned short* kh = k_full + (size_t)h * T_SEQ * 192;
  const unsigned short* vh = v_t    + (size_t)h * 128 * T_SEQ;

  int gK[6], gV[4];
  #pragma unroll
  for (int j = 0; j < 6; j++) {
    int s = tid + j * 256, row = s / 24, cm = s - row * 24;
    gK[j] = row * 192 + (cm ^ (row & 7)) * 8;
  }
  #pragma unroll
  for (int j = 0; j < 4; j++) {
    int s = tid + j * 256, d = s >> 3;
    gV[j] = d * T_SEQ + ((s & 7) ^ (d & 7)) * 8;
  }
  int kxo[12];
  #pragma unroll
  for (int kc = 0; kc < 12; kc++)
    kxo[kc] = (kq * 32 + l31) * 192 + ((kc * 2 + l5) ^ x7) * 8;
  int vxb[2];
  #pragma unroll
  for (int ntv = 0; ntv < 2; ntv++) vxb[ntv] = (kq * 64 + ntv * 32 + l31) * 64;

  bf16x8 qf[12];
  {
    const unsigned short* qrow =
        q_cat + (size_t)(qb * 64 + rq * 32 + l31) * 3072 + h * 192 + l5 * 8;
    #pragma unroll
    for (int kc = 0; kc < 12; kc++) qf[kc] = *(const bf16x8*)(qrow + kc * 16);
  }
  f32x16 oacc[2];
  for (int i = 0; i < 2; i++) oacc[i] = (f32x16)(0.f);
  float lsum[16];
  #pragma unroll
  for (int r = 0; r < 16; r++) lsum[r] = 0.f;
  int rl[16];
  #pragma unroll
  for (int r = 0; r < 16; r++) rl[r] = (r & 3) + 8 * (r >> 2) + 4 * l5;

  #pragma unroll
  for (int j = 0; j < 6; j++) async16(kh + gK[j], &Ksm[0][(tid + j * 256) * 8]);

  int cur = 0;
  for (int kb = 0; kb <= qb; kb++) {
    __syncthreads();                            // K[cur] ready; prev PV readers done
    {
      const unsigned short* vb = vh + kb * 64;
      #pragma unroll
      for (int j = 0; j < 4; j++) async16(vb + gV[j], &Vsm[(tid + j * 256) * 8]);
    }
    const unsigned short* Ks = Ksm[cur];
    f32x16 sacc = (f32x16)(0.f);
    #pragma unroll
    for (int kc = 0; kc < 12; kc++) {
      bf16x8 kf = *(const bf16x8*)(Ks + kxo[kc]);
      sacc = __builtin_amdgcn_mfma_f32_32x32x16_bf16(qf[kc], kf, sacc, 0, 0, 0);
    }
    if (kb == qb) {
      int col_g = kb * 64 + kq * 32 + l31;
      int row_b = qb * 64 + rq * 32;
      #pragma unroll
      for (int r = 0; r < 16; r++)
        if (col_g > row_b + rl[r]) sacc[r] = -1e30f;
    }
    #pragma unroll
    for (int r = 0; r < 16; r++) {
      float p = __expf(sacc[r]);
      sacc[r] = p;
      lsum[r] += p;
    }
    #pragma unroll
    for (int r = 0; r < 16; r++)
      Psm[(rq * 32 + rl[r]) * PP + kq * 32 + l31] = f2bf(sacc[r]);
    __syncthreads();                            // V ready, P visible, K[cur] reads done
    if (kb < qb) {
      const unsigned short* kb1 = kh + (size_t)(kb + 1) * 64 * 192;
      #pragma unroll
      for (int j = 0; j < 6; j++) async16(kb1 + gK[j], &Ksm[cur ^ 1][(tid + j * 256) * 8]);
    }
    #pragma unroll
    for (int kc = 0; kc < 4; kc++) {
      bf16x8 pf = *(const bf16x8*)(Psm + (rq * 32 + l31) * PP + kc * 16 + l5 * 8);
      #pragma unroll
      for (int ntv = 0; ntv < 2; ntv++) {
        bf16x8 vf = *(const bf16x8*)(Vsm + vxb[ntv] + ((kc * 2 + l5) ^ x7) * 8);
        oacc[ntv] = __builtin_amdgcn_mfma_f32_32x32x16_bf16(pf, vf, oacc[ntv], 0, 0, 0);
      }
    }
    cur ^= 1;
  }

  #pragma unroll
  for (int r = 0; r < 16; r++) {
    float s = lsum[r];
    s += __shfl_xor(s, 1, 64);
    s += __shfl_xor(s, 2, 64);
    s += __shfl_xor(s, 4, 64);
    s += __shfl_xor(s, 8, 64);
    s += __shfl_xor(s, 16, 64);
    lsum[r] = s;
  }
  if (l31 == 0)
    #pragma unroll
    for (int r = 0; r < 16; r++) Lred[kq][rq * 32 + rl[r]] = lsum[r];
  __syncthreads();
  #pragma unroll
  for (int r = 0; r < 16; r++) {
    int row_l = rq * 32 + rl[r];
    float inv = 1.f / (Lred[0][row_l] + Lred[1][row_l]);
    int row_g = qb * 64 + row_l;
    #pragma unroll
    for (int ntv = 0; ntv < 2; ntv++)
      attn_out[(size_t)row_g * 2048 + h * 128 + kq * 64 + ntv * 32 + l31] =
          f2bf(oacc[ntv][r] * inv);
  }
}

// ---------------- launch ----------------
extern "C" void kernel_launch(void* const* d_in, const int* in_sizes, int n_in,
                              void* d_out, int out_size, void* d_ws, size_t ws_size,
                              hipStream_t stream) {
  const int*   positions = (const int*)d_in[0];
  const float* hs     = (const float*)d_in[1];
  const float* w_q    = (const float*)d_in[2];
  const float* w_kv_a = (const float*)d_in[3];
  const float* ln_w   = (const float*)d_in[4];
  const float* w_kv_b = (const float*)d_in[5];
  const float* w_o    = (const float*)d_in[6];
  float* out = (float*)d_out;

  char* ws = (char*)d_ws;
  size_t off = 0;
  auto alloc = [&](size_t bytes) { void* p = ws + off; off += (bytes + 255) & ~(size_t)255; return p; };
  unsigned short* hs_bf   = (unsigned short*)alloc((size_t)2048 * 2048 * 2);
  unsigned short* wcat_t  = (unsigned short*)alloc((size_t)NPAD1 * 2048 * 2);
  float*          lat     = (float*)alloc((size_t)2048 * 640 * 4);
  unsigned short* q_cat   = (unsigned short*)alloc((size_t)2048 * 3072 * 2);
  unsigned short* kv_a_bf = (unsigned short*)alloc((size_t)2048 * 512 * 2);
  unsigned short* wkvb_t  = (unsigned short*)alloc((size_t)4096 * 512 * 2);
  unsigned short* kv_b    = (unsigned short*)alloc((size_t)2048 * 4096 * 2);
  unsigned short* k_pe    = (unsigned short*)alloc((size_t)2048 * 64 * 2);
  unsigned short* k_full  = (unsigned short*)alloc((size_t)NHEAD * 2048 * 192 * 2);
  unsigned short* v_t     = (unsigned short*)alloc((size_t)NHEAD * 128 * 2048 * 2);
  unsigned short* attn_o  = (unsigned short*)alloc((size_t)2048 * 2048 * 2);
  unsigned short* wo_t    = (unsigned short*)alloc((size_t)2048 * 2048 * 2);

  prep_kernel<<<7520, 256, 0, stream>>>(hs, w_q, w_kv_a, w_kv_b, w_o,
                                        hs_bf, wcat_t, wkvb_t, wo_t);
  gemm_bt_kernel<128, 2><<<dim3(16, 29), 256, 0, stream>>>(
      hs_bf, wcat_t, q_cat, lat, 2048, NPAD1, 2048);
  postproc1_kernel<<<2048, 256, 0, stream>>>(lat, ln_w, positions, kv_a_bf, q_cat, k_pe);
  gemm_bt_kernel<128, 1><<<dim3(16, 32), 256, 0, stream>>>(
      kv_a_bf, wkvb_t, kv_b, nullptr, 2048, 4096, 512);
  kvpost_kernel<<<7168, 256, 0, stream>>>(kv_b, k_pe, k_full, v_t);
  flash_kernel<<<dim3(16, 32), 256, 0, stream>>>(q_cat, k_full, v_t, attn_o);
  gemm_bt_kernel<64, 0><<<dim3(32, 16), 256, 0, stream>>>(
      attn_o, wo_t, out, nullptr, 2048, 2048, 2048);
}